// Round 3
// baseline (332.066 us; speedup 1.0000x reference)
//
#include <hip/hip_runtime.h>
#include <hip/hip_bf16.h>
#include <math.h>

#define BB   32
#define NN   64
#define NGG  100
#define NBB  128
#define NFF  256
#define NITER 3
#define KPAD 128   // NG=100 padded to MFMA K multiple

typedef __attribute__((ext_vector_type(8))) short short8;
typedef __attribute__((ext_vector_type(4))) float f32x4;

static __device__ __forceinline__ unsigned short f2bf(float f) {
    __hip_bfloat16 h = __float2bfloat16(f);
    return *reinterpret_cast<unsigned short*>(&h);
}
static __device__ __forceinline__ float bf2f(unsigned short u) {
    union { unsigned int i; float f; } v; v.i = ((unsigned int)u) << 16; return v.f;
}

static __device__ __forceinline__ float fast_exp2(float x) {
#if __has_builtin(__builtin_amdgcn_exp2f)
    return __builtin_amdgcn_exp2f(x);
#else
    float r; asm("v_exp_f32 %0, %1" : "=v"(r) : "v"(x)); return r;
#endif
}
static __device__ __forceinline__ float fast_rcp(float x) {
#if __has_builtin(__builtin_amdgcn_rcpf)
    return __builtin_amdgcn_rcpf(x);
#else
    float r; asm("v_rcp_f32 %0, %1" : "=v"(r) : "v"(x)); return r;
#endif
}
// tanh(x) = 1 - 2/(e^{2x}+1); e^{2x} = 2^(x*2/ln2). Saturates correctly at +/-inf.
static __device__ __forceinline__ float fast_tanh(float x) {
    float p = fast_exp2(x * 2.8853900817779268f);
    return 1.0f - 2.0f * fast_rcp(p + 1.0f);
}

// ---------------- embed: X[b,n,:] = W_emb[Z[b,n],:] ----------------
__global__ void embed_kernel(const int* __restrict__ Z, const float* __restrict__ W_emb,
                             float* __restrict__ X) {
    int bn = blockIdx.x, t = threadIdx.x;
    X[bn * NBB + t] = W_emb[Z[bn] * NBB + t];
}

// ---------------- transpose + pad + bf16: dst[c*Kpad+k] = k<K ? src[k*NC+c] : 0 ----------------
__global__ void transpose_pad_kernel(const float* __restrict__ src, unsigned short* __restrict__ dst,
                                     int K, int Kpad, int NC) {
    int idx = blockIdx.x * 256 + threadIdx.x;
    if (idx >= NC * Kpad) return;
    int c = idx / Kpad, k = idx - c * Kpad;
    dst[idx] = (k < K) ? f2bf(src[(size_t)k * NC + c]) : (unsigned short)0;
}

// ---------------- fX = X @ Wi + bi -> bf16, rows with Z==0 zeroed (folds Z_j mask) ----------------
__global__ void fx_kernel(const float* __restrict__ X, const float* __restrict__ Wi,
                          const float* __restrict__ bi, const int* __restrict__ Z,
                          unsigned short* __restrict__ fXb) {
    __shared__ float Xs[NBB];
    int bn = blockIdx.x, t = threadIdx.x;
    if (t < NBB) Xs[t] = X[bn * NBB + t];
    __syncthreads();
    float acc = bi[t];
    for (int k = 0; k < NBB; ++k) acc += Xs[k] * Wi[k * NFF + t];
    fXb[bn * NFF + t] = (Z[bn] > 0) ? f2bf(acc) : (unsigned short)0;
}

// ---------------- interaction (MFMA, swapped-A epilogue, no C staging):
// per (b,i): fV[j,f] = (C[b,i,j,:]@Wc + bc)[f] * fX[b,j,f] ; pre = fV@Wf ;
//            X[b,i,:] += sum_{j!=i} tanh(pre[j,:])
__global__ __launch_bounds__(256, 4) void interact_kernel(
    const int* __restrict__ Z, const float* __restrict__ C,
    const unsigned short* __restrict__ WcT, const float* __restrict__ bc,
    const unsigned short* __restrict__ WfT, const unsigned short* __restrict__ fXb,
    float* __restrict__ X)
{
    __shared__ __align__(16) unsigned short fVs[NN * NFF];  // 32 KB, XOR-swizzled rows

    const int bi_ = blockIdx.x;
    const int b = bi_ >> 6, i = bi_ & 63;
    if (Z[b * NN + i] == 0) return;   // block-uniform early exit: X row unchanged

    const int t = threadIdx.x;
    const int wave = t >> 6, lane = t & 63;
    const int l15 = lane & 15, kg = lane >> 4;

    // ---- phase A: wave owns j-rows [16*wave, 16*wave+16); computes all 256 f ----
    // mfma(A=WcT tile [f x g], B=C^T frags [g x j]) -> D[row=f_local, col=j]
    {
        const int j = wave * 16 + l15;
        const float* Crow = C + ((size_t)bi_ * NN + j) * NGG;

        // B-operand frags: 8 consecutive g's per lane, row j; g>=100 zero-padded
        short8 cf[4];
        #pragma unroll
        for (int ks = 0; ks < 3; ++ks) {
            float4 va = *(const float4*)(Crow + ks * 32 + kg * 8);
            float4 vb = *(const float4*)(Crow + ks * 32 + kg * 8 + 4);
            short8 c;
            c[0] = f2bf(va.x); c[1] = f2bf(va.y); c[2] = f2bf(va.z); c[3] = f2bf(va.w);
            c[4] = f2bf(vb.x); c[5] = f2bf(vb.y); c[6] = f2bf(vb.z); c[7] = f2bf(vb.w);
            cf[ks] = c;
        }
        {
            short8 c = {0, 0, 0, 0, 0, 0, 0, 0};
            if (kg == 0) {  // g = 96..99 valid, rest of ks=3 slot is pad
                float4 va = *(const float4*)(Crow + 96);
                c[0] = f2bf(va.x); c[1] = f2bf(va.y); c[2] = f2bf(va.z); c[3] = f2bf(va.w);
            }
            cf[3] = c;
        }

        const int swz = (j & 7) << 3;
        const unsigned short* fxrow = fXb + ((size_t)(b * NN) + j) * NFF;
        unsigned short* fvrow = fVs + j * NFF;

        #pragma unroll
        for (int ct = 0; ct < 16; ++ct) {
            const int f0 = ct * 16 + kg * 4;
            float4 bcv = *(const float4*)&bc[f0];
            f32x4 acc = {bcv.x, bcv.y, bcv.z, bcv.w};
            #pragma unroll
            for (int ks = 0; ks < 4; ++ks) {
                short8 bw = *(const short8*)&WcT[(size_t)(ct * 16 + l15) * KPAD + ks * 32 + kg * 8];
                acc = __builtin_amdgcn_mfma_f32_16x16x32_bf16(bw, cf[ks], acc, 0, 0, 0);
            }
            // lane holds fC[f0..f0+3] for row j -> vectorized fX mult + 8B LDS write
            ushort4 fx = *(const ushort4*)&fxrow[f0];
            ushort4 o;
            o.x = f2bf(acc[0] * bf2f(fx.x));
            o.y = f2bf(acc[1] * bf2f(fx.y));
            o.z = f2bf(acc[2] * bf2f(fx.z));
            o.w = f2bf(acc[3] * bf2f(fx.w));
            *(ushort4*)&fvrow[f0 ^ swz] = o;
        }
    }
    __syncthreads();

    // ---- phase B: pre = fV @ Wf; wave owns out-cols [32*wave, 32*wave+32) ----
    {
        short8 bwf[2][8];
        #pragma unroll
        for (int ct = 0; ct < 2; ++ct)
            #pragma unroll
            for (int ks = 0; ks < 8; ++ks)
                bwf[ct][ks] = *(const short8*)&WfT[(size_t)(wave * 32 + ct * 16 + l15) * NFF + ks * 32 + kg * 8];

        float vsum0 = 0.f, vsum1 = 0.f;
        #pragma unroll
        for (int jt = 0; jt < 4; ++jt) {
            f32x4 a0 = {0.f, 0.f, 0.f, 0.f}, a1 = {0.f, 0.f, 0.f, 0.f};
            const int r = jt * 16 + l15;
            const int swz = (r & 7) << 3;
            #pragma unroll
            for (int ks = 0; ks < 8; ++ks) {
                short8 af = *(const short8*)&fVs[r * NFF + ((ks * 32 + kg * 8) ^ swz)];
                a0 = __builtin_amdgcn_mfma_f32_16x16x32_bf16(af, bwf[0][ks], a0, 0, 0, 0);
                a1 = __builtin_amdgcn_mfma_f32_16x16x32_bf16(af, bwf[1][ks], a1, 0, 0, 0);
            }
            // D: col=l15 (o), row=kg*4+reg (j within jt tile); Z_j mask already in fXb
            #pragma unroll
            for (int reg = 0; reg < 4; ++reg) {
                int j2 = jt * 16 + kg * 4 + reg;
                float m = (j2 != i) ? 1.f : 0.f;
                vsum0 += m * fast_tanh(a0[reg]);
                vsum1 += m * fast_tanh(a1[reg]);
            }
        }
        vsum0 += __shfl_xor(vsum0, 16); vsum0 += __shfl_xor(vsum0, 32);
        vsum1 += __shfl_xor(vsum1, 16); vsum1 += __shfl_xor(vsum1, 32);
        if (lane < 16) {
            float* Xp = X + (size_t)bi_ * NBB + wave * 32 + lane;
            Xp[0]  += vsum0;
            Xp[16] += vsum1;
        }
    }
}

// ---------------- readout stage A ----------------
__global__ void readoutA_kernel(const int* __restrict__ Z, const float* __restrict__ X,
                                const float* __restrict__ W1, const float* __restrict__ b1,
                                const float* __restrict__ W2, const float* __restrict__ b2,
                                float* __restrict__ yi_buf)
{
    __shared__ float Xs[NBB];
    int bn = blockIdx.x;
    int h = threadIdx.x;      // 0..63
    Xs[h] = X[(size_t)bn * NBB + h];
    Xs[h + 64] = X[(size_t)bn * NBB + h + 64];
    __syncthreads();

    float s = b1[h];
    for (int k = 0; k < NBB; ++k) s += Xs[k] * W1[k * 64 + h];
    float v = tanhf(s) * W2[h];
    #pragma unroll
    for (int off = 32; off > 0; off >>= 1) v += __shfl_down(v, off);
    if (h == 0) {
        int z = Z[bn];
        yi_buf[bn] = (z > 0) ? (v + b2[0]) : 0.f;
    }
}

// ---------------- readout stage B ----------------
__global__ void readoutB_kernel(const float* __restrict__ yi_buf, float* __restrict__ y)
{
    int b = blockIdx.x, i = threadIdx.x;
    float v = yi_buf[b * NN + i];
    #pragma unroll
    for (int off = 32; off > 0; off >>= 1) v += __shfl_down(v, off);
    if (i == 0) y[b] = v;
}

extern "C" void kernel_launch(void* const* d_in, const int* in_sizes, int n_in,
                              void* d_out, int out_size, void* d_ws, size_t ws_size,
                              hipStream_t stream) {
    (void)in_sizes; (void)n_in; (void)out_size; (void)ws_size;
    const int*   Z    = (const int*)d_in[0];
    const float* C    = (const float*)d_in[1];
    const float* Wemb = (const float*)d_in[2];
    const float* Wc   = (const float*)d_in[3];
    const float* bc   = (const float*)d_in[4];
    const float* Wi   = (const float*)d_in[5];
    const float* bi   = (const float*)d_in[6];
    const float* Wf   = (const float*)d_in[7];
    const float* W1   = (const float*)d_in[8];
    const float* b1   = (const float*)d_in[9];
    const float* W2   = (const float*)d_in[10];
    const float* b2   = (const float*)d_in[11];
    float* y = (float*)d_out;

    // ws layout: X f32 [2048*128] | fXb bf16 [2048*256] | WcT bf16 [256*128] | WfT bf16 [128*256] | yi f32 [2048]
    float* X = (float*)d_ws;
    unsigned short* fXb = (unsigned short*)(X + (size_t)BB * NN * NBB);
    unsigned short* WcT = fXb + (size_t)BB * NN * NFF;
    unsigned short* WfT = WcT + (size_t)NFF * KPAD;
    float* yi = (float*)(WfT + (size_t)NBB * NFF);

    embed_kernel<<<BB * NN, NBB, 0, stream>>>(Z, Wemb, X);
    transpose_pad_kernel<<<(NFF * KPAD) / 256, 256, 0, stream>>>(Wc, WcT, NGG, KPAD, NFF);
    transpose_pad_kernel<<<(NBB * NFF) / 256, 256, 0, stream>>>(Wf, WfT, NFF, NFF, NBB);

    for (int it = 0; it < NITER; ++it) {
        fx_kernel<<<BB * NN, NFF, 0, stream>>>(X, Wi, bi, Z, fXb);
        interact_kernel<<<BB * NN, 256, 0, stream>>>(Z, C, WcT, bc, WfT, fXb, X);
    }
    readoutA_kernel<<<BB * NN, 64, 0, stream>>>(Z, X, W1, b1, W2, b2, yi);
    readoutB_kernel<<<BB, NN, 0, stream>>>(yi, y);
}